// Round 4
// baseline (256.495 us; speedup 1.0000x reference)
//
#include <hip/hip_runtime.h>
#include <hip/hip_bf16.h>

#define B_    4
#define N_    16384
#define K_    16
#define CIN_  64
#define CF_   67          // 3 + 64 concat channels
#define COUT_ 128
#define AGGP_ 1088        // 16*68 padded flattening (c=67 slot zero per w-row)
#define P_    16          // points per block
#define FSTR  72          // bf16 record stride in shorts (144 B)
#define ASTR  1096        // agg/FT row stride in shorts (2192 B, 16B-aligned)
#define WTS   272         // s_WT point stride in shorts: [w][k] 16x16 + 16 pad
#define NEG_  0.1f

typedef __attribute__((ext_vector_type(8))) short short8;
typedef __attribute__((ext_vector_type(4))) float f32x4;
typedef __attribute__((ext_vector_type(2))) unsigned int uint2_t;
typedef __attribute__((ext_vector_type(4))) unsigned int uint4_t;

__device__ __forceinline__ unsigned short f2b(float f) {
    __hip_bfloat16 h = __float2bfloat16(f);
    return *reinterpret_cast<unsigned short*>(&h);
}
__device__ __forceinline__ float leaky(float x) { return x >= 0.f ? x : NEG_ * x; }

// ---------------------------------------------------------------------------
// Kernel 1 (fused prep):
//  blocks [0,1024):   transpose concat(xyz,features) -> ft bf16 [B][N][FSTR]
//  blocks [1024,1152): convert lin_w fp32 [128][16*67] -> lwb bf16 [128][16*68]
// ---------------------------------------------------------------------------
__global__ __launch_bounds__(256) void pc_prep(
    const float* __restrict__ xyz,
    const float* __restrict__ feats,
    const float* __restrict__ lin_w,
    unsigned short* __restrict__ ft,
    short* __restrict__ lwb)
{
    const int bid = blockIdx.x, t = threadIdx.x;
    if (bid < 1024) {
        __shared__ float st[64][69];           // [j_local][c], +1 pad
        const int b  = bid >> 8;
        const int j0 = (bid & 255) << 6;
        // load: lane = (c, jq); float4 per thread, coalesced 1 KB per wave instr
        for (int ii = t; ii < 68 * 16; ii += 256) {
            const int c = ii >> 4, jq = ii & 15;
            f32x4 v = {0.f, 0.f, 0.f, 0.f};
            if (c < 3)
                v = *(const f32x4*)(xyz   + ((size_t)b * 3    + c)       * N_ + j0 + 4 * jq);
            else if (c < CF_)
                v = *(const f32x4*)(feats + ((size_t)b * CIN_ + (c - 3)) * N_ + j0 + 4 * jq);
            st[4 * jq + 0][c] = v.x;
            st[4 * jq + 1][c] = v.y;
            st[4 * jq + 2][c] = v.z;
            st[4 * jq + 3][c] = v.w;
        }
        __syncthreads();
        // pack: 9 x uint4 per record (72 shorts), coalesced 16-B stores
        uint4_t* outp4 = (uint4_t*)(ft + (size_t)(b * N_ + j0) * FSTR);
        for (int idx = t; idx < 64 * 9; idx += 256) {
            const int j2 = idx / 9, q = idx - 9 * j2;
            const int cb = q * 8;
            unsigned u[4];
#pragma unroll
            for (int e = 0; e < 4; e++) {
                const int c0 = cb + 2 * e;
                const unsigned lo = (c0     < CF_) ? (unsigned)f2b(st[j2][c0])     : 0u;
                const unsigned hi = (c0 + 1 < CF_) ? (unsigned)f2b(st[j2][c0 + 1]) : 0u;
                u[e] = lo | (hi << 16);
            }
            uint4_t uu = { u[0], u[1], u[2], u[3] };
            outp4[idx] = uu;
        }
    } else {
        const int o = bid - 1024;              // 128 out-channel rows
        const float* src = lin_w + (size_t)o * (16 * CF_);
        short*       dst = lwb   + (size_t)o * AGGP_;
        for (int i = t; i < AGGP_; i += 256) {
            const int w = i / 68, c = i % 68;
            dst[i] = (c < CF_) ? (short)f2b(src[w * CF_ + c]) : (short)0;
        }
    }
}

// ---------------------------------------------------------------------------
// Kernel 2: fused weight-net MLP + MFMA agg einsum + MFMA final linear.
// Phases 1-2 wave-local (wave owns 4 points); single barrier before phase 3.
// FT[c][k] half-slots parity-swizzled by s (=c>>2); phase-2b reads undo via
// khs = kh ^ ((pr&4)<<1)  (validated round 3: conflicts 9.57M->5.37M, ~1:1
// on the critical path).
// Phase 3: INLINE-ASM pipelined A-loads.  Round-3 evidence: a C++-level
// 6-deep prefetch ring was collapsed by the compiler (VGPR stayed 68, gain
// == bank-conflict delta only) -> per-iter exposed L2 latency (~300cy x 34)
// is the dominant kernel stall (~300K idle cyc/CU).  Now the A-panel loads
// are asm-volatile global_load_dwordx4 into an 8-pair ring with literal
// counted s_waitcnt vmcnt(14/12/.../0) + sched_barrier(0) after each wait
// (rule: MFMA hoists past bare asm waits).  In-order vmcnt completion makes
// the counts robust to any compiler loads interleaving (they only tighten).
// LDS 44.8 KB -> 3 blocks/CU.  __launch_bounds__(256,2).
// ---------------------------------------------------------------------------

// async 16-B global load into a short8 register quad (compiler does NOT
// track this in its waitcnt bookkeeping -- we wait manually)
#define PC_GLOAD(dst, p) \
    __asm__ __volatile__("global_load_dwordx4 %0, %1, off" \
                         : "=v"(dst) : "v"(p) : "memory")

// one pipeline step: wait until pair ks has landed (W = outstanding allowed,
// literal), fence the scheduler, consume, issue pair ks+8.
#define PC_STEP(ks, W) do { \
    __asm__ __volatile__("s_waitcnt vmcnt(" W ")"); \
    __builtin_amdgcn_sched_barrier(0); \
    if ((ks) + 8 < 34) { \
        PC_GLOAD(r0[(ks) + 8], a0p + 32 * ((ks) + 8)); \
        PC_GLOAD(r1[(ks) + 8], a1p + 32 * ((ks) + 8)); \
    } \
    const short8 bfr##ks = *(const short8*)(bp + 32 * (ks)); \
    acc0 = __builtin_amdgcn_mfma_f32_16x16x32_bf16(r0[(ks)], bfr##ks, acc0, 0, 0, 0); \
    acc1 = __builtin_amdgcn_mfma_f32_16x16x32_bf16(r1[(ks)], bfr##ks, acc1, 0, 0, 0); \
} while (0)

__global__ __launch_bounds__(256, 2) void pc_main(
    const float*          __restrict__ xyz,
    const unsigned short* __restrict__ ft,
    const int*            __restrict__ knn,
    const float* __restrict__ w1, const float* __restrict__ b1,
    const float* __restrict__ w2, const float* __restrict__ b2,
    const short* __restrict__ lwb, const float* __restrict__ lin_b,
    float* __restrict__ out)
{
    __shared__ __align__(16) short s_agg[P_ * ASTR];   // FT[c][k] then agg[w*68+c]
    __shared__ __align__(16) short s_WT[P_ * WTS];     // [p][w*16+k] bf16
    __shared__ int s_idx[P_ * K_];

    const int t   = threadIdx.x;
    const int bid = blockIdx.x;            // 4096
    const int b   = bid >> 10;
    const int n0  = (bid & 1023) << 4;
    const unsigned short* ftb = ft + (size_t)b * N_ * FSTR;

    // ---------------- phase 1: weight-net MLP, one thread per (p,k) --------
    {
        const int p = t >> 4, k = t & 15;
        const int n = n0 + p;
        const int j = knn[((size_t)(b * N_ + n)) * K_ + k];
        s_idx[p * K_ + k] = j;
        const float* xb = xyz + (size_t)b * 3 * N_;   // fp32-exact MLP input
        const float dx0 = xb[j]          - xb[n];
        const float dx1 = xb[N_ + j]     - xb[N_ + n];
        const float dx2 = xb[2 * N_ + j] - xb[2 * N_ + n];
        float h[8];
#pragma unroll
        for (int i = 0; i < 8; i++)
            h[i] = leaky(b1[i] + w1[i*3+0]*dx0 + w1[i*3+1]*dx1 + w1[i*3+2]*dx2);
        short* wd = s_WT + p * WTS + k;               // WT[p][w][k], stride 16
#pragma unroll
        for (int w = 0; w < 16; w++) {
            float a = b2[w];
#pragma unroll
            for (int i = 0; i < 8; i++) a += w2[w*8+i] * h[i];
            wd[w * 16] = (short)f2b(leaky(a));
        }
    }
    __asm__ __volatile__("" ::: "memory");   // wave-local: DS pipe in-order

    // ---------------- phase 2a: gather + register transpose -> FT[c][k] ----
    {
        const int p = t >> 4, s = t & 15;
        const int* ip = s_idx + p * K_;
        const bool tl = (s < 3);
        uint2_t fb[K_];
        unsigned feu[8] = {0,0,0,0,0,0,0,0};
#pragma unroll
        for (int k = 0; k < K_; k++) {
            const unsigned short* rec = ftb + (size_t)ip[k] * FSTR;
            fb[k] = *(const uint2_t*)(rec + 4 * s);
            if (tl) feu[k >> 1] |= ((unsigned)rec[64 + s]) << (16 * (k & 1));
        }
        short* frow = s_agg + p * ASTR;
        const int swz = s & 1;               // parity half-swizzle (s == c>>2)
        const int hf  = swz << 3;            // first-store slot: 0 (even) / 8 (odd)
#pragma unroll
        for (int i = 0; i < 4; i++) {        // rows c = 4s+i, k-contiguous
            const unsigned sel = (i & 1) ? 0x07060302u : 0x05040100u;
            unsigned pk[8];
#pragma unroll
            for (int d = 0; d < 8; d++) {
                const unsigned lo = (i < 2) ? fb[2*d].x   : fb[2*d].y;
                const unsigned hi = (i < 2) ? fb[2*d+1].x : fb[2*d+1].y;
                pk[d] = __builtin_amdgcn_perm(hi, lo, sel);
            }
            const int c = 4 * s + i;
            uint4_t q0 = { pk[0], pk[1], pk[2], pk[3] };   // logical k = 0..7
            uint4_t q1 = { pk[4], pk[5], pk[6], pk[7] };   // logical k = 8..15
            // address alternates by parity; data does NOT (q0 always to hf).
            *(uint4_t*)(frow + c * 16 + hf)       = q0;
            *(uint4_t*)(frow + c * 16 + (8 - hf)) = q1;
        }
        if (tl) {                            // tail rows c = 64..66 (unswizzled)
            uint4_t q0 = { feu[0], feu[1], feu[2], feu[3] };
            uint4_t q1 = { feu[4], feu[5], feu[6], feu[7] };
            *(uint4_t*)(frow + (64 + s) * 16)     = q0;
            *(uint4_t*)(frow + (64 + s) * 16 + 8) = q1;
        }
        if (s == 3) {                        // row 67 = zero (agg[w][67]=0)
            uint4_t z = {0u, 0u, 0u, 0u};
            *(uint4_t*)(frow + 67 * 16)     = z;
            *(uint4_t*)(frow + 67 * 16 + 8) = z;
        }
    }
    __asm__ __volatile__("" ::: "memory");

    // ---------------- phase 2b: pair MFMA agg, overwrite FT with agg -------
    {
        const int lane = t & 63;
        const int wq   = lane >> 4;          // quad
        const int pr   = lane & 15;
        const int pb   = (t >> 6) * 4;       // wave's first point
        const int kh   = (wq & 1) * 8;       // k-halfword within a point
        const int khs  = kh ^ ((pr & 4) << 1);   // undo parity half-swizzle
        const int side = (wq < 2) ? 0 : 1;   // B-operand / D-row point select
        const int asid = (pr < 8) ? 0 : 1;   // A-operand point select
        const bool act = (side == asid);
        const int cq   = 4 * (wq & 1);
#pragma unroll
        for (int pair = 0; pair < 2; pair++) {
            const int pA = pb + 2 * pair;
            const short8 bfr = *(const short8*)(s_WT + (pA + side) * WTS + pr * 16 + kh);
            const short* ap  = s_agg + (size_t)(pA + asid) * ASTR + (pr & 7) * 16 + khs;
            f32x4 D[9];
#pragma unroll
            for (int cc = 0; cc < 9; cc++) {
                short8 af = {0,0,0,0,0,0,0,0};
                // cc=8 reads rows 64..67 only; active lanes there have pr&4==0
                // so khs==kh (rows 64..67 stored unswizzled).
                if (act && (cc < 8 || (pr & 7) < 4))
                    af = *(const short8*)(ap + 128 * cc);
                D[cc] = __builtin_amdgcn_mfma_f32_16x16x32_bf16(
                            af, bfr, (f32x4){0.f,0.f,0.f,0.f}, 0, 0, 0);
            }
            __asm__ __volatile__("" ::: "memory");  // all FT reads before stores
            short* arow = s_agg + (size_t)(pA + side) * ASTR + pr * 68;  // w=pr
#pragma unroll
            for (int cc = 0; cc < 9; cc++) {
                if (cc == 8 && cq != 0) continue;   // c=68..71 skipped
                const unsigned lo = (unsigned)f2b(D[cc].x) | ((unsigned)f2b(D[cc].y) << 16);
                const unsigned hi = (unsigned)f2b(D[cc].z) | ((unsigned)f2b(D[cc].w) << 16);
                uint2_t pk2 = { lo, hi };
                *(uint2_t*)(arow + 8 * cc + cq) = pk2;
            }
        }
    }
    __syncthreads();   // agg complete for all 16 points (drains vmcnt/lgkmcnt)

    // ---------------- phase 3: out[128 x 16] = L[128x1088] @ aggT^T --------
    {
        const int lane = t & 63, wid = t >> 6;
        const int quad = lane >> 4, pr = lane & 15;
        const int kq = quad * 8;
        // A fragment: lane holds A[m=pr][k=quad*8+j]; A row = out channel
        const short* a0p = lwb + (size_t)(wid * 32 + pr) * AGGP_ + kq;
        const short* a1p = a0p + 16 * AGGP_;
        // B fragment: lane holds B[k=quad*8+j][n=pr]; B col = point
        const short* bp  = s_agg + pr * ASTR + kq;
        f32x4 acc0 = {0.f, 0.f, 0.f, 0.f};
        f32x4 acc1 = {0.f, 0.f, 0.f, 0.f};

        // asm 8-pair ring: 16 loads in flight, vmcnt(14) steady-state.
        // All r0/r1 indices are literals (PC_STEP macro) -> registers.
        short8 r0[34], r1[34];
#pragma unroll
        for (int d = 0; d < 8; d++) {
            PC_GLOAD(r0[d], a0p + 32 * d);
            PC_GLOAD(r1[d], a1p + 32 * d);
        }
        PC_STEP(0, "14");  PC_STEP(1, "14");  PC_STEP(2, "14");  PC_STEP(3, "14");
        PC_STEP(4, "14");  PC_STEP(5, "14");  PC_STEP(6, "14");  PC_STEP(7, "14");
        PC_STEP(8, "14");  PC_STEP(9, "14");  PC_STEP(10, "14"); PC_STEP(11, "14");
        PC_STEP(12, "14"); PC_STEP(13, "14"); PC_STEP(14, "14"); PC_STEP(15, "14");
        PC_STEP(16, "14"); PC_STEP(17, "14"); PC_STEP(18, "14"); PC_STEP(19, "14");
        PC_STEP(20, "14"); PC_STEP(21, "14"); PC_STEP(22, "14"); PC_STEP(23, "14");
        PC_STEP(24, "14"); PC_STEP(25, "14"); PC_STEP(26, "14"); PC_STEP(27, "12");
        PC_STEP(28, "10"); PC_STEP(29, "8");  PC_STEP(30, "6");  PC_STEP(31, "4");
        PC_STEP(32, "2");  PC_STEP(33, "0");

        // epilogue: D row = quad*4 + r (out channel within tile), D col = pr
        const int o0 = wid * 32 + quad * 4;
#pragma unroll
        for (int r = 0; r < 4; r++) {
            const int oA = o0 + r;
            const int oB = oA + 16;
            const float vA = leaky(acc0[r] + lin_b[oA]);
            const float vB = leaky(acc1[r] + lin_b[oB]);
            out[((size_t)(b * COUT_ + oA)) * N_ + n0 + pr] = vA;
            out[((size_t)(b * COUT_ + oB)) * N_ + n0 + pr] = vB;
        }
    }
}

extern "C" void kernel_launch(void* const* d_in, const int* in_sizes, int n_in,
                              void* d_out, int out_size, void* d_ws, size_t ws_size,
                              hipStream_t stream)
{
    const float* xyz   = (const float*)d_in[0];
    const float* feats = (const float*)d_in[1];
    const int*   knn   = (const int*)d_in[2];
    const float* w1    = (const float*)d_in[3];
    const float* b1    = (const float*)d_in[4];
    const float* w2    = (const float*)d_in[5];
    const float* b2    = (const float*)d_in[6];
    const float* lin_w = (const float*)d_in[7];
    const float* lin_b = (const float*)d_in[8];
    float* out = (float*)d_out;

    unsigned short* ft = (unsigned short*)d_ws;              // 9.44 MB bf16
    short* lwb = (short*)((char*)d_ws + (size_t)B_ * N_ * FSTR * sizeof(short));
                                                             // 128*1088*2 = 278 KB

    hipLaunchKernelGGL(pc_prep, dim3(1024 + COUT_), dim3(256), 0, stream,
                       xyz, feats, lin_w, ft, lwb);
    hipLaunchKernelGGL(pc_main, dim3(B_ * (N_ / P_)), dim3(256), 0, stream,
                       xyz, ft, knn, w1, b1, w2, b2, lwb, lin_b, out);
}

// Round 5
// 245.425 us; speedup vs baseline: 1.0451x; 1.0451x over previous
//
#include <hip/hip_runtime.h>
#include <hip/hip_bf16.h>

#define B_    4
#define N_    16384
#define K_    16
#define CIN_  64
#define CF_   67          // 3 + 64 concat channels
#define COUT_ 128
#define AGGP_ 1088        // 16*68 padded flattening (c=67 slot zero per w-row)
#define P_    16          // points per block
#define FSTR  72          // bf16 record stride in shorts (144 B)
#define ASTR  1096        // agg/FT row stride in shorts (2192 B, 16B-aligned)
#define WTS   272         // s_WT point stride in shorts: [w][k] 16x16 + 16 pad
#define NEG_  0.1f

typedef __attribute__((ext_vector_type(8))) short short8;
typedef __attribute__((ext_vector_type(4))) float f32x4;
typedef __attribute__((ext_vector_type(2))) unsigned int uint2_t;
typedef __attribute__((ext_vector_type(4))) unsigned int uint4_t;

__device__ __forceinline__ unsigned short f2b(float f) {
    __hip_bfloat16 h = __float2bfloat16(f);
    return *reinterpret_cast<unsigned short*>(&h);
}
__device__ __forceinline__ float leaky(float x) { return x >= 0.f ? x : NEG_ * x; }

// ---------------------------------------------------------------------------
// Kernel 1 (fused prep):
//  blocks [0,1024):   transpose concat(xyz,features) -> ft bf16 [B][N][FSTR]
//  blocks [1024,1152): convert lin_w fp32 [128][16*67] -> lwb bf16 [128][16*68]
// ---------------------------------------------------------------------------
__global__ __launch_bounds__(256) void pc_prep(
    const float* __restrict__ xyz,
    const float* __restrict__ feats,
    const float* __restrict__ lin_w,
    unsigned short* __restrict__ ft,
    short* __restrict__ lwb)
{
    const int bid = blockIdx.x, t = threadIdx.x;
    if (bid < 1024) {
        __shared__ float st[64][69];           // [j_local][c], +1 pad
        const int b  = bid >> 8;
        const int j0 = (bid & 255) << 6;
        for (int ii = t; ii < 68 * 16; ii += 256) {
            const int c = ii >> 4, jq = ii & 15;
            f32x4 v = {0.f, 0.f, 0.f, 0.f};
            if (c < 3)
                v = *(const f32x4*)(xyz   + ((size_t)b * 3    + c)       * N_ + j0 + 4 * jq);
            else if (c < CF_)
                v = *(const f32x4*)(feats + ((size_t)b * CIN_ + (c - 3)) * N_ + j0 + 4 * jq);
            st[4 * jq + 0][c] = v.x;
            st[4 * jq + 1][c] = v.y;
            st[4 * jq + 2][c] = v.z;
            st[4 * jq + 3][c] = v.w;
        }
        __syncthreads();
        uint4_t* outp4 = (uint4_t*)(ft + (size_t)(b * N_ + j0) * FSTR);
        for (int idx = t; idx < 64 * 9; idx += 256) {
            const int j2 = idx / 9, q = idx - 9 * j2;
            const int cb = q * 8;
            unsigned u[4];
#pragma unroll
            for (int e = 0; e < 4; e++) {
                const int c0 = cb + 2 * e;
                const unsigned lo = (c0     < CF_) ? (unsigned)f2b(st[j2][c0])     : 0u;
                const unsigned hi = (c0 + 1 < CF_) ? (unsigned)f2b(st[j2][c0 + 1]) : 0u;
                u[e] = lo | (hi << 16);
            }
            uint4_t uu = { u[0], u[1], u[2], u[3] };
            outp4[idx] = uu;
        }
    } else {
        const int o = bid - 1024;              // 128 out-channel rows
        const float* src = lin_w + (size_t)o * (16 * CF_);
        short*       dst = lwb   + (size_t)o * AGGP_;
        for (int i = t; i < AGGP_; i += 256) {
            const int w = i / 68, c = i % 68;
            dst[i] = (c < CF_) ? (short)f2b(src[w * CF_ + c]) : (short)0;
        }
    }
}

// ---------------------------------------------------------------------------
// Kernel 2: fused weight-net MLP + MFMA agg einsum + MFMA final linear.
// Phases 1-2 wave-local (wave owns 4 points); single barrier before phase 3.
//
// FT[c][k] LDS swizzle v2 (this round).  Per-QUARTER-wave bank math: the 2a
// store bank is (4p + 8*(c&3) + hf/2)%32 and c=4s+i makes 32s vanish mod 32
// -> without swizzle all 16 s-lanes of a quarter collide (16-way).  Round-3
// parity hf re-injected only s&1 (8-way, measured 9.57M->5.37M, time 1:1).
// v2 injects TWO independent s bits:
//   row slot: row = c ^ ((c>>2)&3)        (bijective, stays in group-of-4)
//   k-half:   hf  = ((s>>2)&1) << 3       (q0 at hf, q1 at 8-hf)
// -> store bank = 4p + 8*(i^(s&3)) + 4*((s>>2)&1): 8 banks x 2 lanes = free.
// Reader (2b) recomputes per cc: row=(c0+8cc)^(((c0>>2)+2cc)&3),
// khcc = kh ^ (((cc>>1)&1)<<3).  Tail rows 64..67 are identity under both
// formulas (c>>2=16 -> key 0; bit4(c)=0) and cc=8 active lanes have c0<4.
//
// Phase 3 reverted to round-3 form (best measured 167us): round-4 asm
// pipelining REGRESSED (+9us) -- fences pinned each bfr ds_read against its
// MFMA, exposing DS latency; compiler's own schedule is better.  Latency
// theory refuted twice; conflicts are the evidenced lever.
// LDS 44.8 KB -> 3 blocks/CU.  __launch_bounds__(256,2).
// ---------------------------------------------------------------------------
__global__ __launch_bounds__(256, 2) void pc_main(
    const float*          __restrict__ xyz,
    const unsigned short* __restrict__ ft,
    const int*            __restrict__ knn,
    const float* __restrict__ w1, const float* __restrict__ b1,
    const float* __restrict__ w2, const float* __restrict__ b2,
    const short* __restrict__ lwb, const float* __restrict__ lin_b,
    float* __restrict__ out)
{
    __shared__ __align__(16) short s_agg[P_ * ASTR];   // FT[c][k] then agg[w*68+c]
    __shared__ __align__(16) short s_WT[P_ * WTS];     // [p][w*16+k] bf16
    __shared__ int s_idx[P_ * K_];

    const int t   = threadIdx.x;
    const int bid = blockIdx.x;            // 4096
    const int b   = bid >> 10;
    const int n0  = (bid & 1023) << 4;
    const unsigned short* ftb = ft + (size_t)b * N_ * FSTR;

    // ---------------- phase 1: weight-net MLP, one thread per (p,k) --------
    {
        const int p = t >> 4, k = t & 15;
        const int n = n0 + p;
        const int j = knn[((size_t)(b * N_ + n)) * K_ + k];
        s_idx[p * K_ + k] = j;
        const float* xb = xyz + (size_t)b * 3 * N_;   // fp32-exact MLP input
        const float dx0 = xb[j]          - xb[n];
        const float dx1 = xb[N_ + j]     - xb[N_ + n];
        const float dx2 = xb[2 * N_ + j] - xb[2 * N_ + n];
        float h[8];
#pragma unroll
        for (int i = 0; i < 8; i++)
            h[i] = leaky(b1[i] + w1[i*3+0]*dx0 + w1[i*3+1]*dx1 + w1[i*3+2]*dx2);
        short* wd = s_WT + p * WTS + k;               // WT[p][w][k], stride 16
#pragma unroll
        for (int w = 0; w < 16; w++) {
            float a = b2[w];
#pragma unroll
            for (int i = 0; i < 8; i++) a += w2[w*8+i] * h[i];
            wd[w * 16] = (short)f2b(leaky(a));
        }
    }
    __asm__ __volatile__("" ::: "memory");   // wave-local: DS pipe in-order

    // ---------------- phase 2a: gather + register transpose -> FT[c][k] ----
    {
        const int p = t >> 4, s = t & 15;
        const int* ip = s_idx + p * K_;
        const bool tl = (s < 3);
        uint2_t fb[K_];
        unsigned feu[8] = {0,0,0,0,0,0,0,0};
#pragma unroll
        for (int k = 0; k < K_; k++) {
            const unsigned short* rec = ftb + (size_t)ip[k] * FSTR;
            fb[k] = *(const uint2_t*)(rec + 4 * s);
            if (tl) feu[k >> 1] |= ((unsigned)rec[64 + s]) << (16 * (k & 1));
        }
        short* frow = s_agg + p * ASTR;
        const int hf = ((s >> 2) & 1) << 3;  // k-half slot select (s bit 2)
#pragma unroll
        for (int i = 0; i < 4; i++) {        // rows c = 4s+i, k-contiguous
            const unsigned sel = (i & 1) ? 0x07060302u : 0x05040100u;
            unsigned pk[8];
#pragma unroll
            for (int d = 0; d < 8; d++) {
                const unsigned lo = (i < 2) ? fb[2*d].x   : fb[2*d].y;
                const unsigned hi = (i < 2) ? fb[2*d+1].x : fb[2*d+1].y;
                pk[d] = __builtin_amdgcn_perm(hi, lo, sel);
            }
            const int c   = 4 * s + i;
            const int row = c ^ (s & 3);     // row-slot permutation (s bits 0-1)
            uint4_t q0 = { pk[0], pk[1], pk[2], pk[3] };   // logical k = 0..7
            uint4_t q1 = { pk[4], pk[5], pk[6], pk[7] };   // logical k = 8..15
            *(uint4_t*)(frow + row * 16 + hf)       = q0;
            *(uint4_t*)(frow + row * 16 + (8 - hf)) = q1;
        }
        if (tl) {                            // tail rows c = 64..66 (identity)
            uint4_t q0 = { feu[0], feu[1], feu[2], feu[3] };
            uint4_t q1 = { feu[4], feu[5], feu[6], feu[7] };
            *(uint4_t*)(frow + (64 + s) * 16)     = q0;
            *(uint4_t*)(frow + (64 + s) * 16 + 8) = q1;
        }
        if (s == 3) {                        // row 67 = zero (agg[w][67]=0)
            uint4_t z = {0u, 0u, 0u, 0u};
            *(uint4_t*)(frow + 67 * 16)     = z;
            *(uint4_t*)(frow + 67 * 16 + 8) = z;
        }
    }
    __asm__ __volatile__("" ::: "memory");

    // ---------------- phase 2b: pair MFMA agg, overwrite FT with agg -------
    {
        const int lane = t & 63;
        const int wq   = lane >> 4;          // quad
        const int pr   = lane & 15;
        const int pb   = (t >> 6) * 4;       // wave's first point
        const int kh   = (wq & 1) * 8;       // k-halfword within a point
        const int side = (wq < 2) ? 0 : 1;   // B-operand / D-row point select
        const int asid = (pr < 8) ? 0 : 1;   // A-operand point select
        const bool act = (side == asid);
        const int cq   = 4 * (wq & 1);
        const int c0   = pr & 7;             // A-row base within 8-row stripe
        const int bb   = c0 >> 2;            // = (pr>>2)&1, feeds row-slot key
#pragma unroll
        for (int pair = 0; pair < 2; pair++) {
            const int pA = pb + 2 * pair;
            const short8 bfr = *(const short8*)(s_WT + (pA + side) * WTS + pr * 16 + kh);
            const short* ap  = s_agg + (size_t)(pA + asid) * ASTR;
            f32x4 D[9];
#pragma unroll
            for (int cc = 0; cc < 9; cc++) {
                // row c = c0 + 8cc; stored slot = c ^ ((c>>2)&3), c>>2 = bb+2cc
                const int row  = (c0 + 8 * cc) ^ ((bb + 2 * cc) & 3);
                const int khcc = kh ^ (((cc >> 1) & 1) << 3);
                short8 af = {0,0,0,0,0,0,0,0};
                // cc=8 reads rows 64..67 only; active lanes have c0<4 -> bb=0,
                // key=(0+16)&3=0 and bit4(c)=0: identity (matches tail writes).
                if (act && (cc < 8 || c0 < 4))
                    af = *(const short8*)(ap + row * 16 + khcc);
                D[cc] = __builtin_amdgcn_mfma_f32_16x16x32_bf16(
                            af, bfr, (f32x4){0.f,0.f,0.f,0.f}, 0, 0, 0);
            }
            __asm__ __volatile__("" ::: "memory");  // all FT reads before stores
            short* arow = s_agg + (size_t)(pA + side) * ASTR + pr * 68;  // w=pr
#pragma unroll
            for (int cc = 0; cc < 9; cc++) {
                if (cc == 8 && cq != 0) continue;   // c=68..71 skipped
                const unsigned lo = (unsigned)f2b(D[cc].x) | ((unsigned)f2b(D[cc].y) << 16);
                const unsigned hi = (unsigned)f2b(D[cc].z) | ((unsigned)f2b(D[cc].w) << 16);
                uint2_t pk2 = { lo, hi };
                *(uint2_t*)(arow + 8 * cc + cq) = pk2;
            }
        }
    }
    __syncthreads();   // agg complete for all 16 points

    // ---------------- phase 3: out[128 x 16] = L[128x1088] @ aggT^T --------
    {
        const int lane = t & 63, wid = t >> 6;
        const int quad = lane >> 4, pr = lane & 15;
        const int kq = quad * 8;
        // A fragment: lane holds A[m=pr][k=quad*8+j]; A row = out channel
        const short* a0p = lwb + (size_t)(wid * 32 + pr) * AGGP_ + kq;
        const short* a1p = a0p + 16 * AGGP_;
        // B fragment: lane holds B[k=quad*8+j][n=pr]; B col = point
        const short* bp  = s_agg + pr * ASTR + kq;
        f32x4 acc0 = {0.f, 0.f, 0.f, 0.f};
        f32x4 acc1 = {0.f, 0.f, 0.f, 0.f};

        short8 pa0[6], pa1[6];
#pragma unroll
        for (int d = 0; d < 6; d++) {
            pa0[d] = *(const short8*)(a0p + 32 * d);
            pa1[d] = *(const short8*)(a1p + 32 * d);
        }
#pragma unroll
        for (int ks = 0; ks < 34; ks++) {
            const int d = ks % 6;                      // static under full unroll
            const short8 a0c = pa0[d], a1c = pa1[d];
            if (ks + 6 < 34) {
                pa0[d] = *(const short8*)(a0p + 32 * (ks + 6));
                pa1[d] = *(const short8*)(a1p + 32 * (ks + 6));
            }
            const short8 bfr = *(const short8*)(bp + 32 * ks);
            acc0 = __builtin_amdgcn_mfma_f32_16x16x32_bf16(a0c, bfr, acc0, 0, 0, 0);
            acc1 = __builtin_amdgcn_mfma_f32_16x16x32_bf16(a1c, bfr, acc1, 0, 0, 0);
        }
        // epilogue: D row = quad*4 + r (out channel within tile), D col = pr
        const int o0 = wid * 32 + quad * 4;
#pragma unroll
        for (int r = 0; r < 4; r++) {
            const int oA = o0 + r;
            const int oB = oA + 16;
            const float vA = leaky(acc0[r] + lin_b[oA]);
            const float vB = leaky(acc1[r] + lin_b[oB]);
            out[((size_t)(b * COUT_ + oA)) * N_ + n0 + pr] = vA;
            out[((size_t)(b * COUT_ + oB)) * N_ + n0 + pr] = vB;
        }
    }
}

extern "C" void kernel_launch(void* const* d_in, const int* in_sizes, int n_in,
                              void* d_out, int out_size, void* d_ws, size_t ws_size,
                              hipStream_t stream)
{
    const float* xyz   = (const float*)d_in[0];
    const float* feats = (const float*)d_in[1];
    const int*   knn   = (const int*)d_in[2];
    const float* w1    = (const float*)d_in[3];
    const float* b1    = (const float*)d_in[4];
    const float* w2    = (const float*)d_in[5];
    const float* b2    = (const float*)d_in[6];
    const float* lin_w = (const float*)d_in[7];
    const float* lin_b = (const float*)d_in[8];
    float* out = (float*)d_out;

    unsigned short* ft = (unsigned short*)d_ws;              // 9.44 MB bf16
    short* lwb = (short*)((char*)d_ws + (size_t)B_ * N_ * FSTR * sizeof(short));
                                                             // 128*1088*2 = 278 KB

    hipLaunchKernelGGL(pc_prep, dim3(1024 + COUT_), dim3(256), 0, stream,
                       xyz, feats, lin_w, ft, lwb);
    hipLaunchKernelGGL(pc_main, dim3(B_ * (N_ / P_)), dim3(256), 0, stream,
                       xyz, ft, knn, w1, b1, w2, b2, lwb, lin_b, out);
}

// Round 6
// 220.655 us; speedup vs baseline: 1.1624x; 1.1123x over previous
//
#include <hip/hip_runtime.h>
#include <hip/hip_bf16.h>

#define B_    4
#define N_    16384
#define K_    16
#define CIN_  64
#define CF_   67          // 3 + 64 concat channels
#define COUT_ 128
#define AGGP_ 1088        // 16*68 padded flattening (c=67 slot zero per w-row)
#define P_    32          // points per block (2 passes of 16 through phases 1-2)
#define PH_   16          // points per pass
#define FSTR  72          // bf16 record stride in shorts (144 B)
#define ASTR  1096        // agg/FT row stride in shorts (2192 B, 16B-aligned)
#define WTS   272         // s_WT point stride in shorts: [w][k] 16x16 + 16 pad
#define NEG_  0.1f

typedef __attribute__((ext_vector_type(8))) short short8;
typedef __attribute__((ext_vector_type(4))) float f32x4;
typedef __attribute__((ext_vector_type(2))) unsigned int uint2_t;
typedef __attribute__((ext_vector_type(4))) unsigned int uint4_t;

__device__ __forceinline__ unsigned short f2b(float f) {
    __hip_bfloat16 h = __float2bfloat16(f);
    return *reinterpret_cast<unsigned short*>(&h);
}
__device__ __forceinline__ float leaky(float x) { return x >= 0.f ? x : NEG_ * x; }

// ---------------------------------------------------------------------------
// Kernel 1 (fused prep):
//  blocks [0,1024):   transpose concat(xyz,features) -> ft bf16 [B][N][FSTR]
//  blocks [1024,1152): convert lin_w fp32 [128][16*67] -> lwb bf16 [128][16*68]
// ---------------------------------------------------------------------------
__global__ __launch_bounds__(256) void pc_prep(
    const float* __restrict__ xyz,
    const float* __restrict__ feats,
    const float* __restrict__ lin_w,
    unsigned short* __restrict__ ft,
    short* __restrict__ lwb)
{
    const int bid = blockIdx.x, t = threadIdx.x;
    if (bid < 1024) {
        __shared__ float st[64][69];           // [j_local][c], +1 pad
        const int b  = bid >> 8;
        const int j0 = (bid & 255) << 6;
        for (int ii = t; ii < 68 * 16; ii += 256) {
            const int c = ii >> 4, jq = ii & 15;
            f32x4 v = {0.f, 0.f, 0.f, 0.f};
            if (c < 3)
                v = *(const f32x4*)(xyz   + ((size_t)b * 3    + c)       * N_ + j0 + 4 * jq);
            else if (c < CF_)
                v = *(const f32x4*)(feats + ((size_t)b * CIN_ + (c - 3)) * N_ + j0 + 4 * jq);
            st[4 * jq + 0][c] = v.x;
            st[4 * jq + 1][c] = v.y;
            st[4 * jq + 2][c] = v.z;
            st[4 * jq + 3][c] = v.w;
        }
        __syncthreads();
        uint4_t* outp4 = (uint4_t*)(ft + (size_t)(b * N_ + j0) * FSTR);
        for (int idx = t; idx < 64 * 9; idx += 256) {
            const int j2 = idx / 9, q = idx - 9 * j2;
            const int cb = q * 8;
            unsigned u[4];
#pragma unroll
            for (int e = 0; e < 4; e++) {
                const int c0 = cb + 2 * e;
                const unsigned lo = (c0     < CF_) ? (unsigned)f2b(st[j2][c0])     : 0u;
                const unsigned hi = (c0 + 1 < CF_) ? (unsigned)f2b(st[j2][c0 + 1]) : 0u;
                u[e] = lo | (hi << 16);
            }
            uint4_t uu = { u[0], u[1], u[2], u[3] };
            outp4[idx] = uu;
        }
    } else {
        const int o = bid - 1024;              // 128 out-channel rows
        const float* src = lin_w + (size_t)o * (16 * CF_);
        short*       dst = lwb   + (size_t)o * AGGP_;
        for (int i = t; i < AGGP_; i += 256) {
            const int w = i / 68, c = i % 68;
            dst[i] = (c < CF_) ? (short)f2b(src[w * CF_ + c]) : (short)0;
        }
    }
}

// ---------------------------------------------------------------------------
// Kernel 2: fused weight-net MLP + MFMA agg einsum + MFMA final linear.
// P=32 points/block (this round).  Evidence: round-5 showed pc_main is
// latency-bound (per-wave lifetime 74K cyc vs ~2K issue) with phase 3's
// per-wave 69.6KB lwb L2 stream as the dominant latency x count product,
// refetched every 16 points (1.14 GB L2 total).  Scheduling fixes failed
// twice (rounds 3/4); amortization is the lever: 32 points/block halves
// per-point A-loads, halves lwb traffic (0.57 GB), halves block overhead.
// Phases 1-2 run TWICE (16 points/pass; wave-local, no inter-pass barrier;
// s_WT/s_idx reuse is wave-local-safe).  Phase 3: each wave's A rows feed
// TWO B point-tiles -> 4 MFMA per A-pair (2x MFMA per byte loaded).
// FT[c][k] LDS swizzle v2 (validated round 5: conflicts 5.37M->2.23M):
//   row = c ^ ((c>>2)&3),  k-half hf = ((s>>2)&1)<<3; reader recomputes
//   row=(c0+8cc)^((bb+2cc)&3), khcc=kh^(((cc>>1)&1)<<3); tail rows identity.
// LDS 79.9 KB -> 2 blocks/CU (8 waves/CU, accepted occupancy cost).
// ---------------------------------------------------------------------------
__global__ __launch_bounds__(256, 2) void pc_main(
    const float*          __restrict__ xyz,
    const unsigned short* __restrict__ ft,
    const int*            __restrict__ knn,
    const float* __restrict__ w1, const float* __restrict__ b1,
    const float* __restrict__ w2, const float* __restrict__ b2,
    const short* __restrict__ lwb, const float* __restrict__ lin_b,
    float* __restrict__ out)
{
    __shared__ __align__(16) short s_agg[P_ * ASTR];   // 32 pts: FT[c][k] then agg
    __shared__ __align__(16) short s_WT[PH_ * WTS];    // per-pass [p][w*16+k]
    __shared__ int s_idx[PH_ * K_];                    // per-pass

    const int t   = threadIdx.x;
    const int bid = blockIdx.x;            // 2048
    const int b   = bid >> 9;
    const int n0  = (bid & 511) << 5;      // 32 points per block
    const unsigned short* ftb = ft + (size_t)b * N_ * FSTR;

#pragma unroll
    for (int h = 0; h < 2; h++) {          // two 16-point passes, wave-local
        // ---------------- phase 1: weight-net MLP, one thread per (p,k) ----
        {
            const int p = t >> 4, k = t & 15;
            const int pp = h * PH_ + p;
            const int n = n0 + pp;
            const int j = knn[((size_t)(b * N_ + n)) * K_ + k];
            s_idx[p * K_ + k] = j;
            const float* xb = xyz + (size_t)b * 3 * N_;   // fp32-exact MLP input
            const float dx0 = xb[j]          - xb[n];
            const float dx1 = xb[N_ + j]     - xb[N_ + n];
            const float dx2 = xb[2 * N_ + j] - xb[2 * N_ + n];
            float hh[8];
#pragma unroll
            for (int i = 0; i < 8; i++)
                hh[i] = leaky(b1[i] + w1[i*3+0]*dx0 + w1[i*3+1]*dx1 + w1[i*3+2]*dx2);
            short* wd = s_WT + p * WTS + k;               // WT[p][w][k], stride 16
#pragma unroll
            for (int w = 0; w < 16; w++) {
                float a = b2[w];
#pragma unroll
                for (int i = 0; i < 8; i++) a += w2[w*8+i] * hh[i];
                wd[w * 16] = (short)f2b(leaky(a));
            }
        }
        __asm__ __volatile__("" ::: "memory");   // wave-local: DS pipe in-order

        // ---------------- phase 2a: gather + register transpose -> FT[c][k]
        {
            const int p = t >> 4, s = t & 15;
            const int pp = h * PH_ + p;
            const int* ip = s_idx + p * K_;
            const bool tl = (s < 3);
            uint2_t fb[K_];
            unsigned feu[8] = {0,0,0,0,0,0,0,0};
#pragma unroll
            for (int k = 0; k < K_; k++) {
                const unsigned short* rec = ftb + (size_t)ip[k] * FSTR;
                fb[k] = *(const uint2_t*)(rec + 4 * s);
                if (tl) feu[k >> 1] |= ((unsigned)rec[64 + s]) << (16 * (k & 1));
            }
            short* frow = s_agg + (size_t)pp * ASTR;
            const int hf = ((s >> 2) & 1) << 3;  // k-half slot select (s bit 2)
#pragma unroll
            for (int i = 0; i < 4; i++) {        // rows c = 4s+i, k-contiguous
                const unsigned sel = (i & 1) ? 0x07060302u : 0x05040100u;
                unsigned pk[8];
#pragma unroll
                for (int d = 0; d < 8; d++) {
                    const unsigned lo = (i < 2) ? fb[2*d].x   : fb[2*d].y;
                    const unsigned hi = (i < 2) ? fb[2*d+1].x : fb[2*d+1].y;
                    pk[d] = __builtin_amdgcn_perm(hi, lo, sel);
                }
                const int c   = 4 * s + i;
                const int row = c ^ (s & 3);     // row-slot permutation (s bits 0-1)
                uint4_t q0 = { pk[0], pk[1], pk[2], pk[3] };   // logical k = 0..7
                uint4_t q1 = { pk[4], pk[5], pk[6], pk[7] };   // logical k = 8..15
                *(uint4_t*)(frow + row * 16 + hf)       = q0;
                *(uint4_t*)(frow + row * 16 + (8 - hf)) = q1;
            }
            if (tl) {                            // tail rows c = 64..66 (identity)
                uint4_t q0 = { feu[0], feu[1], feu[2], feu[3] };
                uint4_t q1 = { feu[4], feu[5], feu[6], feu[7] };
                *(uint4_t*)(frow + (64 + s) * 16)     = q0;
                *(uint4_t*)(frow + (64 + s) * 16 + 8) = q1;
            }
            if (s == 3) {                        // row 67 = zero (agg[w][67]=0)
                uint4_t z = {0u, 0u, 0u, 0u};
                *(uint4_t*)(frow + 67 * 16)     = z;
                *(uint4_t*)(frow + 67 * 16 + 8) = z;
            }
        }
        __asm__ __volatile__("" ::: "memory");

        // ---------------- phase 2b: pair MFMA agg, overwrite FT with agg ---
        {
            const int lane = t & 63;
            const int wq   = lane >> 4;          // quad
            const int pr   = lane & 15;
            const int pbl  = (t >> 6) * 4;       // wave's first local point
            const int kh   = (wq & 1) * 8;       // k-halfword within a point
            const int side = (wq < 2) ? 0 : 1;   // B-operand / D-row point select
            const int asid = (pr < 8) ? 0 : 1;   // A-operand point select
            const bool act = (side == asid);
            const int cq   = 4 * (wq & 1);
            const int c0   = pr & 7;             // A-row base within 8-row stripe
            const int bb   = c0 >> 2;            // feeds row-slot key
#pragma unroll
            for (int pair = 0; pair < 2; pair++) {
                const int lpA = pbl + 2 * pair;          // local (pass) point
                const int ppA = h * PH_ + lpA;           // global (block) point
                const short8 bfr = *(const short8*)(s_WT + (lpA + side) * WTS + pr * 16 + kh);
                const short* ap  = s_agg + (size_t)(ppA + asid) * ASTR;
                f32x4 D[9];
#pragma unroll
                for (int cc = 0; cc < 9; cc++) {
                    const int row  = (c0 + 8 * cc) ^ ((bb + 2 * cc) & 3);
                    const int khcc = kh ^ (((cc >> 1) & 1) << 3);
                    short8 af = {0,0,0,0,0,0,0,0};
                    // cc=8 reads rows 64..67 only; active lanes have c0<4 ->
                    // bb=0, key 0, bit4(c)=0: identity (matches tail writes).
                    if (act && (cc < 8 || c0 < 4))
                        af = *(const short8*)(ap + row * 16 + khcc);
                    D[cc] = __builtin_amdgcn_mfma_f32_16x16x32_bf16(
                                af, bfr, (f32x4){0.f,0.f,0.f,0.f}, 0, 0, 0);
                }
                __asm__ __volatile__("" ::: "memory");  // all FT reads before stores
                short* arow = s_agg + (size_t)(ppA + side) * ASTR + pr * 68;  // w=pr
#pragma unroll
                for (int cc = 0; cc < 9; cc++) {
                    if (cc == 8 && cq != 0) continue;   // c=68..71 skipped
                    const unsigned lo = (unsigned)f2b(D[cc].x) | ((unsigned)f2b(D[cc].y) << 16);
                    const unsigned hi = (unsigned)f2b(D[cc].z) | ((unsigned)f2b(D[cc].w) << 16);
                    uint2_t pk2 = { lo, hi };
                    *(uint2_t*)(arow + 8 * cc + cq) = pk2;
                }
            }
        }
        __asm__ __volatile__("" ::: "memory");
    }

    // ---------------- phase 3: out[128 x 32] = L[128x1088] @ aggT^T --------
    {
        const int lane = t & 63, wid = t >> 6;
        const int quad = lane >> 4, pr = lane & 15;
        const int kq = quad * 8;
        // A fragment: lane holds A[m=pr][k=quad*8+j]; A row = out channel
        const short* a0p = lwb + (size_t)(wid * 32 + pr) * AGGP_ + kq;
        const short* a1p = a0p + 16 * AGGP_;

        // issue A prologue BEFORE the barrier: lwb loads are independent of
        // s_agg, so they overlap phase-2b tails + barrier wait.
        short8 pa0[6], pa1[6];
#pragma unroll
        for (int d = 0; d < 6; d++) {
            pa0[d] = *(const short8*)(a0p + 32 * d);
            pa1[d] = *(const short8*)(a1p + 32 * d);
        }
        __syncthreads();   // agg complete for all 32 points

        // B fragments: two point-tiles share every A load (4 MFMA / A-pair)
        const short* bp0 = s_agg + (size_t)pr * ASTR + kq;          // pts 0..15
        const short* bp1 = s_agg + (size_t)(16 + pr) * ASTR + kq;   // pts 16..31
        f32x4 acc00 = {0.f, 0.f, 0.f, 0.f};   // a0 x b0
        f32x4 acc01 = {0.f, 0.f, 0.f, 0.f};   // a0 x b1
        f32x4 acc10 = {0.f, 0.f, 0.f, 0.f};   // a1 x b0
        f32x4 acc11 = {0.f, 0.f, 0.f, 0.f};   // a1 x b1

#pragma unroll
        for (int ks = 0; ks < 34; ks++) {
            const int d = ks % 6;                      // static under full unroll
            const short8 a0c = pa0[d], a1c = pa1[d];
            if (ks + 6 < 34) {
                pa0[d] = *(const short8*)(a0p + 32 * (ks + 6));
                pa1[d] = *(const short8*)(a1p + 32 * (ks + 6));
            }
            const short8 b0 = *(const short8*)(bp0 + 32 * ks);
            const short8 b1 = *(const short8*)(bp1 + 32 * ks);
            acc00 = __builtin_amdgcn_mfma_f32_16x16x32_bf16(a0c, b0, acc00, 0, 0, 0);
            acc01 = __builtin_amdgcn_mfma_f32_16x16x32_bf16(a0c, b1, acc01, 0, 0, 0);
            acc10 = __builtin_amdgcn_mfma_f32_16x16x32_bf16(a1c, b0, acc10, 0, 0, 0);
            acc11 = __builtin_amdgcn_mfma_f32_16x16x32_bf16(a1c, b1, acc11, 0, 0, 0);
        }
        // epilogue: D row = quad*4 + r (out channel within tile), D col = pr
        const int o0 = wid * 32 + quad * 4;
#pragma unroll
        for (int r = 0; r < 4; r++) {
            const int oA = o0 + r;
            const int oB = oA + 16;
            const float bA = lin_b[oA], bB = lin_b[oB];
            float* rowA = out + ((size_t)(b * COUT_ + oA)) * N_ + n0;
            float* rowB = out + ((size_t)(b * COUT_ + oB)) * N_ + n0;
            rowA[pr]      = leaky(acc00[r] + bA);
            rowA[16 + pr] = leaky(acc01[r] + bA);
            rowB[pr]      = leaky(acc10[r] + bB);
            rowB[16 + pr] = leaky(acc11[r] + bB);
        }
    }
}

extern "C" void kernel_launch(void* const* d_in, const int* in_sizes, int n_in,
                              void* d_out, int out_size, void* d_ws, size_t ws_size,
                              hipStream_t stream)
{
    const float* xyz   = (const float*)d_in[0];
    const float* feats = (const float*)d_in[1];
    const int*   knn   = (const int*)d_in[2];
    const float* w1    = (const float*)d_in[3];
    const float* b1    = (const float*)d_in[4];
    const float* w2    = (const float*)d_in[5];
    const float* b2    = (const float*)d_in[6];
    const float* lin_w = (const float*)d_in[7];
    const float* lin_b = (const float*)d_in[8];
    float* out = (float*)d_out;

    unsigned short* ft = (unsigned short*)d_ws;              // 9.44 MB bf16
    short* lwb = (short*)((char*)d_ws + (size_t)B_ * N_ * FSTR * sizeof(short));
                                                             // 128*1088*2 = 278 KB

    hipLaunchKernelGGL(pc_prep, dim3(1024 + COUT_), dim3(256), 0, stream,
                       xyz, feats, lin_w, ft, lwb);
    hipLaunchKernelGGL(pc_main, dim3(B_ * (N_ / P_)), dim3(256), 0, stream,
                       xyz, ft, knn, w1, b1, w2, b2, lwb, lin_b, out);
}

// Round 8
// 206.812 us; speedup vs baseline: 1.2402x; 1.0669x over previous
//
#include <hip/hip_runtime.h>
#include <hip/hip_bf16.h>

#define B_    4
#define N_    16384
#define K_    16
#define CIN_  64
#define CF_   67          // 3 + 64 concat channels
#define COUT_ 128
#define AGGP_ 1088        // 16*68 padded flattening (c=67 slot zero per w-row)
#define P_    32          // points per block (2 passes of 16 through phases 1-2)
#define PH_   16          // points per pass
#define FSTR  72          // bf16 record stride in shorts (144 B)
#define ASTR  1096        // agg/FT row stride in shorts (2192 B, 16B-aligned)
#define WTS   272         // s_WT point stride in shorts: [w][k] 16x16 + 16 pad
#define NEG_  0.1f

typedef __attribute__((ext_vector_type(8))) short short8;
typedef __attribute__((ext_vector_type(4))) float f32x4;
typedef __attribute__((ext_vector_type(2))) unsigned int uint2_t;
typedef __attribute__((ext_vector_type(4))) unsigned int uint4_t;

__device__ __forceinline__ unsigned short f2b(float f) {
    __hip_bfloat16 h = __float2bfloat16(f);
    return *reinterpret_cast<unsigned short*>(&h);
}
__device__ __forceinline__ float leaky(float x) { return x >= 0.f ? x : NEG_ * x; }

// ---------------------------------------------------------------------------
// Kernel 1 (fused prep):
//  blocks [0,1024):   transpose concat(xyz,features) -> ft bf16 [B][N][FSTR]
//                     + interleaved fp32 xyz3 [B][N][4] (1-line coord gathers)
//  blocks [1024,1152): convert lin_w fp32 [128][16*67] -> lwb bf16 [128][16*68]
// ---------------------------------------------------------------------------
__global__ __launch_bounds__(256) void pc_prep(
    const float* __restrict__ xyz,
    const float* __restrict__ feats,
    const float* __restrict__ lin_w,
    unsigned short* __restrict__ ft,
    short* __restrict__ lwb,
    float* __restrict__ xyz3)
{
    const int bid = blockIdx.x, t = threadIdx.x;
    if (bid < 1024) {
        __shared__ float st[64][69];           // [j_local][c], +1 pad
        const int b  = bid >> 8;
        const int j0 = (bid & 255) << 6;
        for (int ii = t; ii < 68 * 16; ii += 256) {
            const int c = ii >> 4, jq = ii & 15;
            f32x4 v = {0.f, 0.f, 0.f, 0.f};
            if (c < 3)
                v = *(const f32x4*)(xyz   + ((size_t)b * 3    + c)       * N_ + j0 + 4 * jq);
            else if (c < CF_)
                v = *(const f32x4*)(feats + ((size_t)b * CIN_ + (c - 3)) * N_ + j0 + 4 * jq);
            st[4 * jq + 0][c] = v.x;
            st[4 * jq + 1][c] = v.y;
            st[4 * jq + 2][c] = v.z;
            st[4 * jq + 3][c] = v.w;
        }
        __syncthreads();
        if (t < 64) {                          // fp32 interleaved coords
            f32x4 v = { st[t][0], st[t][1], st[t][2], 0.f };
            *(f32x4*)(xyz3 + ((size_t)(b * N_ + j0 + t)) * 4) = v;
        }
        uint4_t* outp4 = (uint4_t*)(ft + (size_t)(b * N_ + j0) * FSTR);
        for (int idx = t; idx < 64 * 9; idx += 256) {
            const int j2 = idx / 9, q = idx - 9 * j2;
            const int cb = q * 8;
            unsigned u[4];
#pragma unroll
            for (int e = 0; e < 4; e++) {
                const int c0 = cb + 2 * e;
                const unsigned lo = (c0     < CF_) ? (unsigned)f2b(st[j2][c0])     : 0u;
                const unsigned hi = (c0 + 1 < CF_) ? (unsigned)f2b(st[j2][c0 + 1]) : 0u;
                u[e] = lo | (hi << 16);
            }
            uint4_t uu = { u[0], u[1], u[2], u[3] };
            outp4[idx] = uu;
        }
    } else {
        const int o = bid - 1024;              // 128 out-channel rows
        const float* src = lin_w + (size_t)o * (16 * CF_);
        short*       dst = lwb   + (size_t)o * AGGP_;
        for (int i = t; i < AGGP_; i += 256) {
            const int w = i / 68, c = i % 68;
            dst[i] = (c < CF_) ? (short)f2b(src[w * CF_ + c]) : (short)0;
        }
    }
}

// ------------------------- pc_main phase helpers ---------------------------
__device__ __forceinline__ void gather_ft(const unsigned short* ftb, const int* ip,
                                          int s, bool tl, uint2_t* fb, unsigned* feu)
{
#pragma unroll
    for (int k = 0; k < K_; k++) {
        const unsigned short* rec = ftb + (size_t)ip[k] * FSTR;
        fb[k] = *(const uint2_t*)(rec + 4 * s);
        if (tl) feu[k >> 1] |= ((unsigned)rec[64 + s]) << (16 * (k & 1));
    }
}

__device__ __forceinline__ void mlp_store(
    short* wd, float d0, float d1, float d2,
    const float* w1, const float* b1, const float* w2, const float* b2)
{
    float hh[8];
#pragma unroll
    for (int i = 0; i < 8; i++)
        hh[i] = leaky(b1[i] + w1[i*3+0]*d0 + w1[i*3+1]*d1 + w1[i*3+2]*d2);
#pragma unroll
    for (int w = 0; w < 16; w++) {
        float a = b2[w];
#pragma unroll
        for (int i = 0; i < 8; i++) a += w2[w*8+i] * hh[i];
        wd[w * 16] = (short)f2b(leaky(a));
    }
}

// FT[c][k] LDS swizzle v2 (validated round 5: conflicts 5.37M->2.23M):
//   row = c ^ ((c>>2)&3),  k-half hf = ((s>>2)&1)<<3 (q0 at hf, q1 at 8-hf)
__device__ __forceinline__ void transpose_store(
    short* frow, const uint2_t* fb, const unsigned* feu, int s, bool tl)
{
    const int hf = ((s >> 2) & 1) << 3;
#pragma unroll
    for (int i = 0; i < 4; i++) {            // rows c = 4s+i, k-contiguous
        const unsigned sel = (i & 1) ? 0x07060302u : 0x05040100u;
        unsigned pk[8];
#pragma unroll
        for (int d = 0; d < 8; d++) {
            const unsigned lo = (i < 2) ? fb[2*d].x   : fb[2*d].y;
            const unsigned hi = (i < 2) ? fb[2*d+1].x : fb[2*d+1].y;
            pk[d] = __builtin_amdgcn_perm(hi, lo, sel);
        }
        const int c   = 4 * s + i;
        const int row = c ^ (s & 3);
        uint4_t q0 = { pk[0], pk[1], pk[2], pk[3] };
        uint4_t q1 = { pk[4], pk[5], pk[6], pk[7] };
        *(uint4_t*)(frow + row * 16 + hf)       = q0;
        *(uint4_t*)(frow + row * 16 + (8 - hf)) = q1;
    }
    if (tl) {                                // tail rows c = 64..66 (identity)
        uint4_t q0 = { feu[0], feu[1], feu[2], feu[3] };
        uint4_t q1 = { feu[4], feu[5], feu[6], feu[7] };
        *(uint4_t*)(frow + (64 + s) * 16)     = q0;
        *(uint4_t*)(frow + (64 + s) * 16 + 8) = q1;
    }
    if (s == 3) {                            // row 67 = zero (agg[w][67]=0)
        uint4_t z = {0u, 0u, 0u, 0u};
        *(uint4_t*)(frow + 67 * 16)     = z;
        *(uint4_t*)(frow + 67 * 16 + 8) = z;
    }
}

__device__ __forceinline__ void agg_mfma(short* s_aggp, const short* s_WTp,
                                         int t, int pbase)
{
    const int lane = t & 63;
    const int wq   = lane >> 4;          // quad
    const int pr   = lane & 15;
    const int pbl  = (t >> 6) * 4;       // wave's first local point
    const int kh   = (wq & 1) * 8;
    const int side = (wq < 2) ? 0 : 1;   // B-operand / D-row point select
    const int asid = (pr < 8) ? 0 : 1;   // A-operand point select
    const bool act = (side == asid);
    const int cq   = 4 * (wq & 1);
    const int c0   = pr & 7;
    const int bb   = c0 >> 2;
#pragma unroll
    for (int pair = 0; pair < 2; pair++) {
        const int lpA = pbl + 2 * pair;          // local (pass) point
        const int ppA = pbase + lpA;             // global (block) point
        const short8 bfr = *(const short8*)(s_WTp + (lpA + side) * WTS + pr * 16 + kh);
        const short* ap  = s_aggp + (size_t)(ppA + asid) * ASTR;
        f32x4 D[9];
#pragma unroll
        for (int cc = 0; cc < 9; cc++) {
            const int row  = (c0 + 8 * cc) ^ ((bb + 2 * cc) & 3);
            const int khcc = kh ^ (((cc >> 1) & 1) << 3);
            short8 af = {0,0,0,0,0,0,0,0};
            // cc=8 reads rows 64..67 only; active lanes have c0<4 -> bb=0,
            // key 0, bit4(c)=0: identity (matches tail writes).
            if (act && (cc < 8 || c0 < 4))
                af = *(const short8*)(ap + row * 16 + khcc);
            D[cc] = __builtin_amdgcn_mfma_f32_16x16x32_bf16(
                        af, bfr, (f32x4){0.f,0.f,0.f,0.f}, 0, 0, 0);
        }
        __asm__ __volatile__("" ::: "memory");  // all FT reads before stores
        short* arow = s_aggp + (size_t)(ppA + side) * ASTR + pr * 68;  // w=pr
#pragma unroll
        for (int cc = 0; cc < 9; cc++) {
            if (cc == 8 && cq != 0) continue;   // c=68..71 skipped
            const unsigned lo = (unsigned)f2b(D[cc].x) | ((unsigned)f2b(D[cc].y) << 16);
            const unsigned hi = (unsigned)f2b(D[cc].z) | ((unsigned)f2b(D[cc].w) << 16);
            uint2_t pk2 = { lo, hi };
            *(uint2_t*)(arow + 8 * cc + cq) = pk2;
        }
    }
}

// ---------------------------------------------------------------------------
// Kernel 2.  Round-7 restructure: pc_main is memory-REQUEST bound (all pipes
// <=17% busy at 2 waves/SIMD; ~650 cache-line requests per wave-pass, ~45% of
// kernel cycles in address processing) with a 2x-walked serial chain
// knn->xyz->MLP->ft-gather->transpose->MFMA.  Fixes:
//  (a) xyz3 interleaved fp32 coords: 3 stride-N gathers (192 lines) -> one
//      float4 gather (64 lines); MLP stays fp32-exact.
//  (b) front-load BOTH passes' memory (knn, xyz3, ft-records) before any
//      compute: pass B runs with zero exposed latency; pass A's gathers hide
//      under its MLP.  LDS caps occupancy at 2 waves/SIMD -> 256-VGPR budget,
//      so holding pass-B state in regs (~40 VGPRs) is free.
// LDS 80896 B <= 81920 -> 2 blocks/CU preserved.
// ---------------------------------------------------------------------------
__global__ __launch_bounds__(256, 2) void pc_main(
    const float*          __restrict__ x3,     // [B][N][4] fp32 interleaved
    const unsigned short* __restrict__ ft,
    const int*            __restrict__ knn,
    const float* __restrict__ w1, const float* __restrict__ b1,
    const float* __restrict__ w2, const float* __restrict__ b2,
    const short* __restrict__ lwb, const float* __restrict__ lin_b,
    float* __restrict__ out)
{
    __shared__ __align__(16) short s_agg[P_ * ASTR];   // 32 pts: FT[c][k] then agg
    __shared__ __align__(16) short s_WT[PH_ * WTS];    // per-pass [p][w*16+k]
    __shared__ int s_idx[2 * PH_ * K_];                // both passes

    const int t   = threadIdx.x;
    const int bid = blockIdx.x;            // 2048
    const int b   = bid >> 9;
    const int n0  = (bid & 511) << 5;      // 32 points per block
    const unsigned short* ftb = ft + (size_t)b * N_ * FSTR;
    const f32x4* x3b = (const f32x4*)x3 + (size_t)b * N_;

    const int p = t >> 4, s = t & 15;      // dual role: s = k in MLP, s in 2a
    const bool tl = (s < 3);

    // ---- front-load ALL global memory for both passes ---------------------
    const int n_a = n0 + p, n_b = n0 + PH_ + p;
    const int ja = knn[((size_t)(b * N_ + n_a)) * K_ + s];
    const int jb = knn[((size_t)(b * N_ + n_b)) * K_ + s];
    s_idx[(0 * PH_ + p) * K_ + s] = ja;
    s_idx[(1 * PH_ + p) * K_ + s] = jb;
    const f32x4 qa = x3b[ja], qb = x3b[jb];
    const f32x4 ca = x3b[n_a], cb = x3b[n_b];
    const float dxa0 = qa.x - ca.x, dxa1 = qa.y - ca.y, dxa2 = qa.z - ca.z;
    const float dxb0 = qb.x - cb.x, dxb1 = qb.y - cb.y, dxb2 = qb.z - cb.z;
    __asm__ __volatile__("" ::: "memory");   // s_idx visible (wave-local)

    const int* ipa = s_idx + (0 * PH_ + p) * K_;
    const int* ipb = s_idx + (1 * PH_ + p) * K_;
    uint2_t fbA[K_], fbB[K_];
    unsigned feuA[8] = {0,0,0,0,0,0,0,0};
    unsigned feuB[8] = {0,0,0,0,0,0,0,0};
    gather_ft(ftb, ipa, s, tl, fbA, feuA);   // in flight through pass A
    gather_ft(ftb, ipb, s, tl, fbB, feuB);   // in flight through pass B

    // ============================ PASS A ==================================
    mlp_store(s_WT + p * WTS + s, dxa0, dxa1, dxa2, w1, b1, w2, b2);
    __asm__ __volatile__("" ::: "memory");   // wave-local: DS pipe in-order
    transpose_store(s_agg + (size_t)p * ASTR, fbA, feuA, s, tl);
    __asm__ __volatile__("" ::: "memory");
    agg_mfma(s_agg, s_WT, t, 0);
    __asm__ __volatile__("" ::: "memory");

    // ============================ PASS B ==================================
    mlp_store(s_WT + p * WTS + s, dxb0, dxb1, dxb2, w1, b1, w2, b2);
    __asm__ __volatile__("" ::: "memory");
    transpose_store(s_agg + (size_t)(PH_ + p) * ASTR, fbB, feuB, s, tl);
    __asm__ __volatile__("" ::: "memory");
    agg_mfma(s_agg, s_WT, t, PH_);

    // ---------------- phase 3: out[128 x 32] = L[128x1088] @ aggT^T --------
    {
        const int lane = t & 63, wid = t >> 6;
        const int quad = lane >> 4, pr = lane & 15;
        const int kq = quad * 8;
        // A fragment: lane holds A[m=pr][k=quad*8+j]; A row = out channel
        const short* a0p = lwb + (size_t)(wid * 32 + pr) * AGGP_ + kq;
        const short* a1p = a0p + 16 * AGGP_;

        // A prologue BEFORE the barrier: lwb loads are independent of s_agg
        short8 pa0[6], pa1[6];
#pragma unroll
        for (int d = 0; d < 6; d++) {
            pa0[d] = *(const short8*)(a0p + 32 * d);
            pa1[d] = *(const short8*)(a1p + 32 * d);
        }
        __syncthreads();   // agg complete for all 32 points

        // B fragments: two point-tiles share every A load (4 MFMA / A-pair)
        const short* bp0 = s_agg + (size_t)pr * ASTR + kq;          // pts 0..15
        const short* bp1 = s_agg + (size_t)(16 + pr) * ASTR + kq;   // pts 16..31
        f32x4 acc00 = {0.f, 0.f, 0.f, 0.f};   // a0 x b0
        f32x4 acc01 = {0.f, 0.f, 0.f, 0.f};   // a0 x b1
        f32x4 acc10 = {0.f, 0.f, 0.f, 0.f};   // a1 x b0
        f32x4 acc11 = {0.f, 0.f, 0.f, 0.f};   // a1 x b1

#pragma unroll
        for (int ks = 0; ks < 34; ks++) {
            const int d = ks % 6;                      // static under full unroll
            const short8 a0c = pa0[d], a1c = pa1[d];
            if (ks + 6 < 34) {
                pa0[d] = *(const short8*)(a0p + 32 * (ks + 6));
                pa1[d] = *(const short8*)(a1p + 32 * (ks + 6));
            }
            const short8 b0 = *(const short8*)(bp0 + 32 * ks);
            const short8 b1 = *(const short8*)(bp1 + 32 * ks);
            acc00 = __builtin_amdgcn_mfma_f32_16x16x32_bf16(a0c, b0, acc00, 0, 0, 0);
            acc01 = __builtin_amdgcn_mfma_f32_16x16x32_bf16(a0c, b1, acc01, 0, 0, 0);
            acc10 = __builtin_amdgcn_mfma_f32_16x16x32_bf16(a1c, b0, acc10, 0, 0, 0);
            acc11 = __builtin_amdgcn_mfma_f32_16x16x32_bf16(a1c, b1, acc11, 0, 0, 0);
        }
        // epilogue: D row = quad*4 + r (out channel within tile), D col = pr
        const int o0 = wid * 32 + quad * 4;
#pragma unroll
        for (int r = 0; r < 4; r++) {
            const int oA = o0 + r;
            const int oB = oA + 16;
            const float bA = lin_b[oA], bB = lin_b[oB];
            float* rowA = out + ((size_t)(b * COUT_ + oA)) * N_ + n0;
            float* rowB = out + ((size_t)(b * COUT_ + oB)) * N_ + n0;
            rowA[pr]      = leaky(acc00[r] + bA);
            rowA[16 + pr] = leaky(acc01[r] + bA);
            rowB[pr]      = leaky(acc10[r] + bB);
            rowB[16 + pr] = leaky(acc11[r] + bB);
        }
    }
}

extern "C" void kernel_launch(void* const* d_in, const int* in_sizes, int n_in,
                              void* d_out, int out_size, void* d_ws, size_t ws_size,
                              hipStream_t stream)
{
    const float* xyz   = (const float*)d_in[0];
    const float* feats = (const float*)d_in[1];
    const int*   knn   = (const int*)d_in[2];
    const float* w1    = (const float*)d_in[3];
    const float* b1    = (const float*)d_in[4];
    const float* w2    = (const float*)d_in[5];
    const float* b2    = (const float*)d_in[6];
    const float* lin_w = (const float*)d_in[7];
    const float* lin_b = (const float*)d_in[8];
    float* out = (float*)d_out;

    const size_t ftBytes  = (size_t)B_ * N_ * FSTR * sizeof(short);   // 9.44 MB
    const size_t lwbBytes = (size_t)COUT_ * AGGP_ * sizeof(short);    // 278 KB
    unsigned short* ft   = (unsigned short*)d_ws;
    short*          lwb  = (short*)((char*)d_ws + ftBytes);
    float*          xyz3 = (float*)((char*)d_ws + ftBytes + lwbBytes); // 1 MB

    hipLaunchKernelGGL(pc_prep, dim3(1024 + COUT_), dim3(256), 0, stream,
                       xyz, feats, lin_w, ft, lwb, xyz3);
    hipLaunchKernelGGL(pc_main, dim3(B_ * (N_ / P_)), dim3(256), 0, stream,
                       xyz3, ft, knn, w1, b1, w2, b2, lwb, lin_b, out);
}

// Round 9
// 183.292 us; speedup vs baseline: 1.3994x; 1.1283x over previous
//
#include <hip/hip_runtime.h>
#include <hip/hip_bf16.h>

#define B_    4
#define N_    16384
#define K_    16
#define CIN_  64
#define CF_   67          // 3 + 64 concat channels
#define COUT_ 128
#define AGGP_ 1088        // 16*68 padded flattening (c=67 slot zero per w-row)
#define P_    32          // points per block (2 passes of 16 through phases 1-2)
#define PH_   16          // points per pass
#define FSTR  64          // bf16 record stride in shorts (128 B, 2 aligned lines)
#define ASTR  1096        // agg/FT row stride in shorts (2192 B, 16B-aligned)
#define WTS   272         // s_WT point stride in shorts: [w][k] 16x16 + 16 pad
#define NEG_  0.1f

typedef __attribute__((ext_vector_type(8))) short short8;
typedef __attribute__((ext_vector_type(4))) float f32x4;
typedef __attribute__((ext_vector_type(2))) unsigned int uint2_t;
typedef __attribute__((ext_vector_type(4))) unsigned int uint4_t;

__device__ __forceinline__ unsigned short f2b(float f) {
    __hip_bfloat16 h = __float2bfloat16(f);
    return *reinterpret_cast<unsigned short*>(&h);
}
__device__ __forceinline__ float leaky(float x) { return x >= 0.f ? x : NEG_ * x; }

// ---------------------------------------------------------------------------
// Kernel 1 (fused prep):
//  blocks [0,1024):   features-only bf16 records ft [B][N][64] (128-B aligned)
//                     + interleaved fp32 xyz3 [B][N][4] (1-line coord gathers)
//  blocks [1024,1152): lin_w fp32 [128][16*67] -> lwb bf16 [128][16*68] with
//                     COLUMN PERMUTATION matching pc_main's FT row order:
//                     agg channel j: 0..63 = feats j (lin_w col 3+j),
//                     64..66 = xyz (lin_w col j-64), 67 = zero.
// ---------------------------------------------------------------------------
__global__ __launch_bounds__(256) void pc_prep(
    const float* __restrict__ xyz,
    const float* __restrict__ feats,
    const float* __restrict__ lin_w,
    unsigned short* __restrict__ ft,
    short* __restrict__ lwb,
    float* __restrict__ xyz3)
{
    const int bid = blockIdx.x, t = threadIdx.x;
    if (bid < 1024) {
        __shared__ float st[64][69];           // [j_local][c], +1 pad
        const int b  = bid >> 8;
        const int j0 = (bid & 255) << 6;
        for (int ii = t; ii < 68 * 16; ii += 256) {
            const int c = ii >> 4, jq = ii & 15;
            f32x4 v = {0.f, 0.f, 0.f, 0.f};
            if (c < 3)
                v = *(const f32x4*)(xyz   + ((size_t)b * 3    + c)       * N_ + j0 + 4 * jq);
            else if (c < CF_)
                v = *(const f32x4*)(feats + ((size_t)b * CIN_ + (c - 3)) * N_ + j0 + 4 * jq);
            st[4 * jq + 0][c] = v.x;
            st[4 * jq + 1][c] = v.y;
            st[4 * jq + 2][c] = v.z;
            st[4 * jq + 3][c] = v.w;
        }
        __syncthreads();
        if (t < 64) {                          // fp32 interleaved coords
            f32x4 v = { st[t][0], st[t][1], st[t][2], 0.f };
            *(f32x4*)(xyz3 + ((size_t)(b * N_ + j0 + t)) * 4) = v;
        }
        // pack: 8 x uint4 per record (64 feature shorts), no bounds checks
        uint4_t* outp4 = (uint4_t*)(ft + (size_t)(b * N_ + j0) * FSTR);
        for (int idx = t; idx < 64 * 8; idx += 256) {
            const int j2 = idx >> 3, q = idx & 7;
            const int cb = 3 + q * 8;          // feats channel base in st
            unsigned u[4];
#pragma unroll
            for (int e = 0; e < 4; e++) {
                const int c0 = cb + 2 * e;     // max 65, c0+1 max 66 < 67
                u[e] = (unsigned)f2b(st[j2][c0]) | ((unsigned)f2b(st[j2][c0 + 1]) << 16);
            }
            uint4_t uu = { u[0], u[1], u[2], u[3] };
            outp4[idx] = uu;
        }
    } else {
        const int o = bid - 1024;              // 128 out-channel rows
        const float* src = lin_w + (size_t)o * (16 * CF_);
        short*       dst = lwb   + (size_t)o * AGGP_;
        for (int i = t; i < AGGP_; i += 256) {
            const int w = i / 68, c = i % 68;
            const int sc = (c < 64) ? (3 + c) : (c - 64);  // permuted column
            dst[i] = (c < CF_) ? (short)f2b(src[w * CF_ + sc]) : (short)0;
        }
    }
}

// ------------------------- pc_main phase helpers ---------------------------
__device__ __forceinline__ void gather_ft(const unsigned short* ftb, const int* ip,
                                          int s, uint2_t* fb)
{
#pragma unroll
    for (int k = 0; k < K_; k++) {
        const unsigned short* rec = ftb + (size_t)ip[k] * FSTR;
        fb[k] = *(const uint2_t*)(rec + 4 * s);   // 16 s-lanes = 2 full lines
    }
}

__device__ __forceinline__ void mlp_store(
    short* wd, float d0, float d1, float d2,
    const float* w1, const float* b1, const float* w2, const float* b2)
{
    float hh[8];
#pragma unroll
    for (int i = 0; i < 8; i++)
        hh[i] = leaky(b1[i] + w1[i*3+0]*d0 + w1[i*3+1]*d1 + w1[i*3+2]*d2);
#pragma unroll
    for (int w = 0; w < 16; w++) {
        float a = b2[w];
#pragma unroll
        for (int i = 0; i < 8; i++) a += w2[w*8+i] * hh[i];
        wd[w * 16] = (short)f2b(leaky(a));
    }
}

// FT[c][k] LDS swizzle v2 (validated round 5: conflicts 5.37M->2.23M):
//   row = c ^ (s&3),  k-half hf = ((s>>2)&1)<<3 (q0 at hf, q1 at 8-hf)
// Rows 0..63 = gathered features; rows 64..66 = neighbor xyz (written by
// phase-1 from registers, identity layout); row 67 = zero.
__device__ __forceinline__ void transpose_store(
    short* frow, const uint2_t* fb, int s)
{
    const int hf = ((s >> 2) & 1) << 3;
#pragma unroll
    for (int i = 0; i < 4; i++) {            // rows c = 4s+i, k-contiguous
        const unsigned sel = (i & 1) ? 0x07060302u : 0x05040100u;
        unsigned pk[8];
#pragma unroll
        for (int d = 0; d < 8; d++) {
            const unsigned lo = (i < 2) ? fb[2*d].x   : fb[2*d].y;
            const unsigned hi = (i < 2) ? fb[2*d+1].x : fb[2*d+1].y;
            pk[d] = __builtin_amdgcn_perm(hi, lo, sel);
        }
        const int c   = 4 * s + i;
        const int row = c ^ (s & 3);
        uint4_t q0 = { pk[0], pk[1], pk[2], pk[3] };
        uint4_t q1 = { pk[4], pk[5], pk[6], pk[7] };
        *(uint4_t*)(frow + row * 16 + hf)       = q0;
        *(uint4_t*)(frow + row * 16 + (8 - hf)) = q1;
    }
    if (s == 3) {                            // row 67 = zero (agg[w][67]=0)
        uint4_t z = {0u, 0u, 0u, 0u};
        *(uint4_t*)(frow + 67 * 16)     = z;
        *(uint4_t*)(frow + 67 * 16 + 8) = z;
    }
}

__device__ __forceinline__ void agg_mfma(short* s_aggp, const short* s_WTp,
                                         int t, int pbase)
{
    const int lane = t & 63;
    const int wq   = lane >> 4;          // quad
    const int pr   = lane & 15;
    const int pbl  = (t >> 6) * 4;       // wave's first local point
    const int kh   = (wq & 1) * 8;
    const int side = (wq < 2) ? 0 : 1;   // B-operand / D-row point select
    const int asid = (pr < 8) ? 0 : 1;   // A-operand point select
    const bool act = (side == asid);
    const int cq   = 4 * (wq & 1);
    const int c0   = pr & 7;
    const int bb   = c0 >> 2;
#pragma unroll
    for (int pair = 0; pair < 2; pair++) {
        const int lpA = pbl + 2 * pair;          // local (pass) point
        const int ppA = pbase + lpA;             // global (block) point
        const short8 bfr = *(const short8*)(s_WTp + (lpA + side) * WTS + pr * 16 + kh);
        const short* ap  = s_aggp + (size_t)(ppA + asid) * ASTR;
        f32x4 D[9];
#pragma unroll
        for (int cc = 0; cc < 9; cc++) {
            const int row  = (c0 + 8 * cc) ^ ((bb + 2 * cc) & 3);
            const int khcc = kh ^ (((cc >> 1) & 1) << 3);
            short8 af = {0,0,0,0,0,0,0,0};
            // cc=8 reads rows 64..67 only; active lanes have c0<4 -> bb=0,
            // key 0, bit4(c)=0: identity (matches phase-1 xyz + zero writes).
            if (act && (cc < 8 || c0 < 4))
                af = *(const short8*)(ap + row * 16 + khcc);
            D[cc] = __builtin_amdgcn_mfma_f32_16x16x32_bf16(
                        af, bfr, (f32x4){0.f,0.f,0.f,0.f}, 0, 0, 0);
        }
        __asm__ __volatile__("" ::: "memory");  // all FT reads before stores
        short* arow = s_aggp + (size_t)(ppA + side) * ASTR + pr * 68;  // w=pr
#pragma unroll
        for (int cc = 0; cc < 9; cc++) {
            if (cc == 8 && cq != 0) continue;   // c=68..71 skipped
            const unsigned lo = (unsigned)f2b(D[cc].x) | ((unsigned)f2b(D[cc].y) << 16);
            const unsigned hi = (unsigned)f2b(D[cc].z) | ((unsigned)f2b(D[cc].w) << 16);
            uint2_t pk2 = { lo, hi };
            *(uint2_t*)(arow + 8 * cc + cq) = pk2;
        }
    }
}

// ---------------------------------------------------------------------------
// Kernel 2.  Round-9: 128-B feature-only ft records (FSTR 72->64).  Round-8
// confirmed the request/serial-chain model (front-load: 156->124us, VGPR
// 88->120).  Remaining front-end waste was the record FORMAT: 144-B records
// span 3 lines, and channels 64..66 needed a divergent tail gather (48
// scattered 2-B loads/wave) while channels 0..2 (xyz) were ALREADY in
// registers from the x3 MLP gather.  Now: records = 64 feature channels
// (2 aligned lines, no tail); FT rows 64..66 = neighbor xyz written from
// qa/qb registers by phase-1 (identity layout, proven cc=8 reader path);
// lwb columns permuted to match.  Numerics identical (same bf16 rounding).
// LDS 80896 B -> 2 blocks/CU.  __launch_bounds__(256,2).
// ---------------------------------------------------------------------------
__global__ __launch_bounds__(256, 2) void pc_main(
    const float*          __restrict__ x3,     // [B][N][4] fp32 interleaved
    const unsigned short* __restrict__ ft,
    const int*            __restrict__ knn,
    const float* __restrict__ w1, const float* __restrict__ b1,
    const float* __restrict__ w2, const float* __restrict__ b2,
    const short* __restrict__ lwb, const float* __restrict__ lin_b,
    float* __restrict__ out)
{
    __shared__ __align__(16) short s_agg[P_ * ASTR];   // 32 pts: FT[c][k] then agg
    __shared__ __align__(16) short s_WT[PH_ * WTS];    // per-pass [p][w*16+k]
    __shared__ int s_idx[2 * PH_ * K_];                // both passes

    const int t   = threadIdx.x;
    const int bid = blockIdx.x;            // 2048
    const int b   = bid >> 9;
    const int n0  = (bid & 511) << 5;      // 32 points per block
    const unsigned short* ftb = ft + (size_t)b * N_ * FSTR;
    const f32x4* x3b = (const f32x4*)x3 + (size_t)b * N_;

    const int p = t >> 4, s = t & 15;      // dual role: s = k in MLP, s in 2a

    // ---- front-load ALL global memory for both passes ---------------------
    const int n_a = n0 + p, n_b = n0 + PH_ + p;
    const int ja = knn[((size_t)(b * N_ + n_a)) * K_ + s];
    const int jb = knn[((size_t)(b * N_ + n_b)) * K_ + s];
    s_idx[(0 * PH_ + p) * K_ + s] = ja;
    s_idx[(1 * PH_ + p) * K_ + s] = jb;
    const f32x4 qa = x3b[ja], qb = x3b[jb];
    const f32x4 ca = x3b[n_a], cb = x3b[n_b];
    const float dxa0 = qa.x - ca.x, dxa1 = qa.y - ca.y, dxa2 = qa.z - ca.z;
    const float dxb0 = qb.x - cb.x, dxb1 = qb.y - cb.y, dxb2 = qb.z - cb.z;
    __asm__ __volatile__("" ::: "memory");   // s_idx visible (wave-local)

    const int* ipa = s_idx + (0 * PH_ + p) * K_;
    const int* ipb = s_idx + (1 * PH_ + p) * K_;
    uint2_t fbA[K_], fbB[K_];
    gather_ft(ftb, ipa, s, fbA);             // in flight through pass A
    gather_ft(ftb, ipb, s, fbB);             // in flight through pass B

    // ============================ PASS A ==================================
    {   // FT rows 64..66 = neighbor xyz, straight from registers (identity)
        short* frow = s_agg + (size_t)p * ASTR;
        frow[64 * 16 + s] = (short)f2b(qa.x);
        frow[65 * 16 + s] = (short)f2b(qa.y);
        frow[66 * 16 + s] = (short)f2b(qa.z);
    }
    mlp_store(s_WT + p * WTS + s, dxa0, dxa1, dxa2, w1, b1, w2, b2);
    __asm__ __volatile__("" ::: "memory");   // wave-local: DS pipe in-order
    transpose_store(s_agg + (size_t)p * ASTR, fbA, s);
    __asm__ __volatile__("" ::: "memory");
    agg_mfma(s_agg, s_WT, t, 0);
    __asm__ __volatile__("" ::: "memory");

    // ============================ PASS B ==================================
    {
        short* frow = s_agg + (size_t)(PH_ + p) * ASTR;
        frow[64 * 16 + s] = (short)f2b(qb.x);
        frow[65 * 16 + s] = (short)f2b(qb.y);
        frow[66 * 16 + s] = (short)f2b(qb.z);
    }
    mlp_store(s_WT + p * WTS + s, dxb0, dxb1, dxb2, w1, b1, w2, b2);
    __asm__ __volatile__("" ::: "memory");
    transpose_store(s_agg + (size_t)(PH_ + p) * ASTR, fbB, s);
    __asm__ __volatile__("" ::: "memory");
    agg_mfma(s_agg, s_WT, t, PH_);

    // ---------------- phase 3: out[128 x 32] = L[128x1088] @ aggT^T --------
    {
        const int lane = t & 63, wid = t >> 6;
        const int quad = lane >> 4, pr = lane & 15;
        const int kq = quad * 8;
        // A fragment: lane holds A[m=pr][k=quad*8+j]; A row = out channel
        const short* a0p = lwb + (size_t)(wid * 32 + pr) * AGGP_ + kq;
        const short* a1p = a0p + 16 * AGGP_;

        // A prologue BEFORE the barrier: lwb loads are independent of s_agg
        short8 pa0[6], pa1[6];
#pragma unroll
        for (int d = 0; d < 6; d++) {
            pa0[d] = *(const short8*)(a0p + 32 * d);
            pa1[d] = *(const short8*)(a1p + 32 * d);
        }
        __syncthreads();   // agg complete for all 32 points

        // B fragments: two point-tiles share every A load (4 MFMA / A-pair)
        const short* bp0 = s_agg + (size_t)pr * ASTR + kq;          // pts 0..15
        const short* bp1 = s_agg + (size_t)(16 + pr) * ASTR + kq;   // pts 16..31
        f32x4 acc00 = {0.f, 0.f, 0.f, 0.f};   // a0 x b0
        f32x4 acc01 = {0.f, 0.f, 0.f, 0.f};   // a0 x b1
        f32x4 acc10 = {0.f, 0.f, 0.f, 0.f};   // a1 x b0
        f32x4 acc11 = {0.f, 0.f, 0.f, 0.f};   // a1 x b1

#pragma unroll
        for (int ks = 0; ks < 34; ks++) {
            const int d = ks % 6;                      // static under full unroll
            const short8 a0c = pa0[d], a1c = pa1[d];
            if (ks + 6 < 34) {
                pa0[d] = *(const short8*)(a0p + 32 * (ks + 6));
                pa1[d] = *(const short8*)(a1p + 32 * (ks + 6));
            }
            const short8 b0 = *(const short8*)(bp0 + 32 * ks);
            const short8 b1 = *(const short8*)(bp1 + 32 * ks);
            acc00 = __builtin_amdgcn_mfma_f32_16x16x32_bf16(a0c, b0, acc00, 0, 0, 0);
            acc01 = __builtin_amdgcn_mfma_f32_16x16x32_bf16(a0c, b1, acc01, 0, 0, 0);
            acc10 = __builtin_amdgcn_mfma_f32_16x16x32_bf16(a1c, b0, acc10, 0, 0, 0);
            acc11 = __builtin_amdgcn_mfma_f32_16x16x32_bf16(a1c, b1, acc11, 0, 0, 0);
        }
        // epilogue: D row = quad*4 + r (out channel within tile), D col = pr
        const int o0 = wid * 32 + quad * 4;
#pragma unroll
        for (int r = 0; r < 4; r++) {
            const int oA = o0 + r;
            const int oB = oA + 16;
            const float bA = lin_b[oA], bB = lin_b[oB];
            float* rowA = out + ((size_t)(b * COUT_ + oA)) * N_ + n0;
            float* rowB = out + ((size_t)(b * COUT_ + oB)) * N_ + n0;
            rowA[pr]      = leaky(acc00[r] + bA);
            rowA[16 + pr] = leaky(acc01[r] + bA);
            rowB[pr]      = leaky(acc10[r] + bB);
            rowB[16 + pr] = leaky(acc11[r] + bB);
        }
    }
}

extern "C" void kernel_launch(void* const* d_in, const int* in_sizes, int n_in,
                              void* d_out, int out_size, void* d_ws, size_t ws_size,
                              hipStream_t stream)
{
    const float* xyz   = (const float*)d_in[0];
    const float* feats = (const float*)d_in[1];
    const int*   knn   = (const int*)d_in[2];
    const float* w1    = (const float*)d_in[3];
    const float* b1    = (const float*)d_in[4];
    const float* w2    = (const float*)d_in[5];
    const float* b2    = (const float*)d_in[6];
    const float* lin_w = (const float*)d_in[7];
    const float* lin_b = (const float*)d_in[8];
    float* out = (float*)d_out;

    const size_t ftBytes  = (size_t)B_ * N_ * FSTR * sizeof(short);   // 8.39 MB
    const size_t lwbBytes = (size_t)COUT_ * AGGP_ * sizeof(short);    // 278 KB
    unsigned short* ft   = (unsigned short*)d_ws;
    short*          lwb  = (short*)((char*)d_ws + ftBytes);
    float*          xyz3 = (float*)((char*)d_ws + ftBytes + lwbBytes); // 1 MB

    hipLaunchKernelGGL(pc_prep, dim3(1024 + COUT_), dim3(256), 0, stream,
                       xyz, feats, lin_w, ft, lwb, xyz3);
    hipLaunchKernelGGL(pc_main, dim3(B_ * (N_ / P_)), dim3(256), 0, stream,
                       xyz3, ft, knn, w1, b1, w2, b2, lwb, lin_b, out);
}